// Round 10
// baseline (387.372 us; speedup 1.0000x reference)
//
#include <hip/hip_runtime.h>
#include <hip/hip_bf16.h>

// MoE: B=2,S=2048 -> T=4096 tokens, H=1024, F=2048, E=8, TOPK=2
#define TT 4096
#define HH 1024
#define FF 2048
#define EE 8
#define NC32 2048   // EE*FF*HH / (256*32) conv chunks per weight tensor

typedef short short8_t __attribute__((ext_vector_type(8)));
typedef float f32x4 __attribute__((ext_vector_type(4)));

__device__ __forceinline__ unsigned short f2b(float f) {
  union { float f; unsigned u; } v; v.f = f;
  return (unsigned short)((v.u + 0x7fffu + ((v.u >> 16) & 1u)) >> 16);  // RNE
}

__device__ __forceinline__ void gload16(const unsigned short* g, void* l) {
  __builtin_amdgcn_global_load_lds(
      (const __attribute__((address_space(1))) void*)g,
      (__attribute__((address_space(3))) void*)l, 16, 0, 0);
}

#define FENCE asm volatile("" ::: "memory")

// Batched-ILP f32->bf16 conv: 8 independent float4 loads in flight per thread.
__device__ __forceinline__ void conv_ilp(const float* __restrict__ src,
                                         unsigned short* __restrict__ dst,
                                         int c, int tid) {
  size_t base = (size_t)c * 8192 + tid * 4;
  float4 v[8];
#pragma unroll
  for (int j = 0; j < 8; ++j)
    v[j] = *reinterpret_cast<const float4*>(src + base + j * 1024);
#pragma unroll
  for (int j = 0; j < 8; ++j) {
    ushort4 b4;
    b4.x = f2b(v[j].x); b4.y = f2b(v[j].y); b4.z = f2b(v[j].z); b4.w = f2b(v[j].w);
    *reinterpret_cast<ushort4*>(dst + base + j * 1024) = b4;
  }
}

// -------- Front: router (atomic-free) + batched-ILP w1/w3[/w2] convs ------------
__global__ __launch_bounds__(256) void front_kernel(
    const float* __restrict__ x, const float* __restrict__ gw,
    const float* __restrict__ w1, const float* __restrict__ w3,
    const float* __restrict__ w2,
    float* __restrict__ out_logits, float* __restrict__ final_out,
    unsigned short* __restrict__ xbf,
    unsigned short* __restrict__ w1bf, unsigned short* __restrict__ w3bf,
    unsigned short* __restrict__ w2bf,
    int* __restrict__ sel01, float2* __restrict__ w01)
{
  int tid = threadIdx.x;
  int b = blockIdx.x;
  if (b >= TT) {
    int cb = b - TT;
    if (cb < NC32)          conv_ilp(w1, w1bf, cb, tid);
    else if (cb < 2 * NC32) conv_ilp(w3, w3bf, cb - NC32, tid);
    else                    conv_ilp(w2, w2bf, cb - 2 * NC32, tid);
    return;
  }
  int t = b;

  __shared__ float xs[HH];
  __shared__ float lg[EE];

  float4 v = reinterpret_cast<const float4*>(x + (size_t)t * HH)[tid];
  xs[tid * 4 + 0] = v.x; xs[tid * 4 + 1] = v.y;
  xs[tid * 4 + 2] = v.z; xs[tid * 4 + 3] = v.w;
  ushort4 b4;
  b4.x = f2b(v.x); b4.y = f2b(v.y); b4.z = f2b(v.z); b4.w = f2b(v.w);
  reinterpret_cast<ushort4*>(xbf + (size_t)t * HH)[tid] = b4;
  float4 z4; z4.x = z4.y = z4.z = z4.w = 0.f;
  reinterpret_cast<float4*>(final_out + (size_t)t * HH)[tid] = z4;
  __syncthreads();

  int lane = tid & 63, wv = tid >> 6;
  for (int e = wv; e < EE; e += 4) {
    float s = 0.f;
    const float* g = gw + (size_t)e * HH;
#pragma unroll
    for (int j = 0; j < HH / 64; ++j) s += xs[lane + j * 64] * g[lane + j * 64];
#pragma unroll
    for (int off = 32; off > 0; off >>= 1) s += __shfl_down(s, off);
    if (lane == 0) lg[e] = s;
  }
  __syncthreads();

  if (tid < 8) out_logits[(size_t)t * EE + tid] = lg[tid];
  if (tid == 0) {
    float l[EE];
#pragma unroll
    for (int e = 0; e < EE; ++e) l[e] = lg[e];
    int e0 = 0;
#pragma unroll
    for (int e = 1; e < EE; ++e) if (l[e] > l[e0]) e0 = e;
    int e1 = -1;
#pragma unroll
    for (int e = 0; e < EE; ++e) if (e != e0 && (e1 < 0 || l[e] > l[e1])) e1 = e;
    float p1 = expf(l[e1] - l[e0]);
    float w0 = 1.f / (1.f + p1);
    float w1v = p1 * w0;
    sel01[t] = e0 | (e1 << 8);
    w01[t] = make_float2(w0, w1v);
  }
}

// -------- Build: per-expert compacted token lists, atomic-free, deterministic ----
__global__ __launch_bounds__(256) void build_kernel(
    const int* __restrict__ sel01, const float2* __restrict__ w01,
    int* __restrict__ counts, int* __restrict__ tokidx, float* __restrict__ rww)
{
  int e = blockIdx.x;
  int tid = threadIdx.x, lane = tid & 63, wv = tid >> 6;
  __shared__ int wsum[4];
  int base = 0;
  for (int t0 = 0; t0 < TT; t0 += 256) {
    int t = t0 + tid;
    int s = sel01[t];
    int e0 = s & 255, e1 = (s >> 8) & 255;
    bool hit = (e0 == e) || (e1 == e);
    float w = 0.f;
    if (hit) { float2 ww = w01[t]; w = (e0 == e) ? ww.x : ww.y; }
    unsigned long long m = __ballot(hit);
    int wpre = __popcll(m & ((1ull << lane) - 1));
    if (lane == 63) wsum[wv] = wpre + (hit ? 1 : 0);
    __syncthreads();
    int wbase = base;
    for (int q = 0; q < wv; ++q) wbase += wsum[q];
    if (hit) {
      int pos = wbase + wpre;
      tokidx[e * TT + pos] = t;
      rww[e * TT + pos] = w;
    }
    base += wsum[0] + wsum[1] + wsum[2] + wsum[3];
    __syncthreads();
  }
  if (tid == 0) counts[e] = base;
}

// -------- Standalone conv for w2 (fallback when ws too small: after up_gate) ----
__global__ __launch_bounds__(256) void conv_kernel(
    const float* __restrict__ src, unsigned short* __restrict__ dst)
{
  conv_ilp(src, dst, blockIdx.x, threadIdx.x);
}

// -------- Up-proj + gate: A direct global->reg, B-only LDS (2x16KB slots) -------
// Slot layout (bytes): B1[0,8192) 64x64, B3[8192,16384) 64x64.
// B swizzle: 16B-block ^= (row&7) on pre-swizzled SOURCE + swizzled ds_read.
__global__ __launch_bounds__(256) void up_gate_kernel(
    const unsigned short* __restrict__ xbf,
    const unsigned short* __restrict__ w1bf, const unsigned short* __restrict__ w3bf,
    const int* __restrict__ counts, const int* __restrict__ tokidx,
    unsigned short* __restrict__ gated)
{
  int e = blockIdx.z;
  int n = counts[e];
  int row0 = blockIdx.y * 128;
  if (row0 >= n) return;
  int fbase = blockIdx.x * 64;

  int pe = 0;
  for (int q = 0; q < e; ++q) pe += (counts[q] + 127) & ~127;

  __shared__ __align__(16) char lds[2 * 16384];   // 32 KB

  int tid = threadIdx.x;
  int lane = tid & 63, wv = tid >> 6;
  int sb = (tid & 7) ^ ((tid >> 3) & 7);   // swizzled source 16B-block

  // B staging sources (rows (tid>>3)+32j of the 64-row panels)
  const unsigned short* gb1[2];
  const unsigned short* gb3[2];
#pragma unroll
  for (int j = 0; j < 2; ++j) {
    size_t rw_ = (size_t)e * FF + fbase + (tid >> 3) + 32 * j;
    gb1[j] = w1bf + rw_ * HH + sb * 8;
    gb3[j] = w3bf + rw_ * HH + sb * 8;
  }

  int wr = (wv >> 1) * 64, wc = (wv & 1) * 32;
  int fr = lane & 15, kq = lane >> 4, l7 = lane & 7;

  // A-fragment direct-global pointers: lane reads row wr+m*16+fr, col kq*8
  const unsigned short* pA[4];
#pragma unroll
  for (int m = 0; m < 4; ++m) {
    int r = min(row0 + wr + m * 16 + fr, n - 1);
    pA[m] = xbf + (size_t)tokidx[e * TT + r] * HH + kq * 8;
  }

  f32x4 acc1[4][2], acc3[4][2];
#pragma unroll
  for (int m = 0; m < 4; ++m)
#pragma unroll
    for (int nn = 0; nn < 2; ++nn) { acc1[m][nn] = (f32x4)0.f; acc3[m][nn] = (f32x4)0.f; }

#define UG_STAGE(T, SOFF) do {                                                   \
    _Pragma("unroll") for (int j = 0; j < 2; ++j) {                              \
      gload16(gb1[j] + (T) * 64, lds + (SOFF) + j * 4096 + wv * 1024);           \
      gload16(gb3[j] + (T) * 64, lds + (SOFF) + 8192 + j * 4096 + wv * 1024);    \
    } } while (0)

#define UG_PHASE(SOFF, KS, AV) do {                                                         \
    int bswz = (((KS) * 4 + kq) ^ l7) * 16;                                                 \
    short8_t b1f[2], b3f[2];                                                                \
    _Pragma("unroll") for (int nn = 0; nn < 2; ++nn) {                                      \
      b1f[nn] = *(const short8_t*)(lds + (SOFF) + (wc + nn * 16 + fr) * 128 + bswz);        \
      b3f[nn] = *(const short8_t*)(lds + (SOFF) + 8192 + (wc + nn * 16 + fr) * 128 + bswz); \
    }                                                                                       \
    __builtin_amdgcn_s_setprio(1);                                                          \
    _Pragma("unroll") for (int m = 0; m < 4; ++m)                                           \
      _Pragma("unroll") for (int nn = 0; nn < 2; ++nn) {                                    \
        acc1[m][nn] = __builtin_amdgcn_mfma_f32_16x16x32_bf16(AV[m], b1f[nn], acc1[m][nn], 0, 0, 0); \
        acc3[m][nn] = __builtin_amdgcn_mfma_f32_16x16x32_bf16(AV[m], b3f[nn], acc3[m][nn], 0, 0, 0); \
      }                                                                                     \
    __builtin_amdgcn_s_setprio(0);                                                          \
  } while (0)

#define UG_NT 16
#define UG_ITER(T, SOFF) do {                                          \
    asm volatile("s_waitcnt vmcnt(4)" ::: "memory");                   \
    __builtin_amdgcn_s_barrier(); FENCE;                               \
    short8_t av0_[4], av1_[4];                                         \
    _Pragma("unroll") for (int m = 0; m < 4; ++m) {                    \
      av0_[m] = *(const short8_t*)(pA[m] + (T) * 64);                  \
      av1_[m] = *(const short8_t*)(pA[m] + (T) * 64 + 32);             \
    }                                                                  \
    UG_PHASE(SOFF, 0, av0_);                                           \
    UG_PHASE(SOFF, 1, av1_);                                           \
    FENCE; __builtin_amdgcn_s_barrier(); FENCE;                        \
    if ((T) + 2 < UG_NT) UG_STAGE((T) + 2, SOFF);                      \
  } while (0)

  UG_STAGE(0, 0);
  UG_STAGE(1, 16384);
  for (int t2 = 0; t2 < UG_NT; t2 += 2) { UG_ITER(t2, 0); UG_ITER(t2 + 1, 16384); }
#undef UG_STAGE
#undef UG_PHASE
#undef UG_ITER

  // epilogue: gated = silu(h1)*h3 -> bf16
  size_t gbase = ((size_t)pe + row0) * FF + fbase;
#pragma unroll
  for (int m = 0; m < 4; ++m) {
#pragma unroll
    for (int nn = 0; nn < 2; ++nn) {
      f32x4 h1v = acc1[m][nn], h3v = acc3[m][nn];
#pragma unroll
      for (int j = 0; j < 4; ++j) {
        float z = h1v[j];
        float val = (z / (1.f + expf(-z))) * h3v[j];
        int r = wr + m * 16 + (lane >> 4) * 4 + j;
        int c = wc + nn * 16 + fr;
        gated[gbase + (size_t)r * FF + c] = f2b(val);
      }
    }
  }
}

// -------- Down-proj + scatter: A (gated) direct global->reg, B-only LDS ---------
// Slot layout (bytes): B[0,16384) 128x64.
__global__ __launch_bounds__(256) void down_kernel(
    const unsigned short* __restrict__ gated,
    const unsigned short* __restrict__ w2bf,
    const int* __restrict__ counts, const int* __restrict__ tokidx,
    const float* __restrict__ rww,
    float* __restrict__ final_out)
{
  int e = blockIdx.z;
  int n = counts[e];
  int row0 = blockIdx.y * 128;
  if (row0 >= n) return;
  int hbase = blockIdx.x * 128;
  int valid = min(128, n - row0);

  int pe = 0;
  for (int q = 0; q < e; ++q) pe += (counts[q] + 127) & ~127;

  __shared__ __align__(16) char lds[2 * 16384];   // 32 KB

  int tid = threadIdx.x;
  int lane = tid & 63, wv = tid >> 6;
  int sb = (tid & 7) ^ ((tid >> 3) & 7);

  const unsigned short* gb[4];
#pragma unroll
  for (int j = 0; j < 4; ++j)
    gb[j] = w2bf + ((size_t)e * HH + hbase + (tid >> 3) + 32 * j) * FF + sb * 8;

  int wr = (wv >> 1) * 64, wc = (wv & 1) * 64;
  int fr = lane & 15, kq = lane >> 4, l7 = lane & 7;

  // A-fragment direct-global pointers (gated is compacted+padded: no clamp)
  const unsigned short* pA[4];
#pragma unroll
  for (int m = 0; m < 4; ++m)
    pA[m] = gated + ((size_t)pe + row0 + wr + m * 16 + fr) * FF + kq * 8;

  f32x4 acc[4][4];
#pragma unroll
  for (int m = 0; m < 4; ++m)
#pragma unroll
    for (int nn = 0; nn < 4; ++nn) acc[m][nn] = (f32x4)0.f;

#define DN_STAGE(T, SOFF) do {                                                   \
    _Pragma("unroll") for (int j = 0; j < 4; ++j)                                \
      gload16(gb[j] + (T) * 64, lds + (SOFF) + j * 4096 + wv * 1024);            \
  } while (0)

#define DN_PHASE(SOFF, KS, AV) do {                                                        \
    int bswz = (((KS) * 4 + kq) ^ l7) * 16;                                                \
    short8_t bf[4];                                                                        \
    _Pragma("unroll") for (int nn = 0; nn < 4; ++nn)                                       \
      bf[nn] = *(const short8_t*)(lds + (SOFF) + (wc + nn * 16 + fr) * 128 + bswz);        \
    __builtin_amdgcn_s_setprio(1);                                                         \
    _Pragma("unroll") for (int m = 0; m < 4; ++m)                                          \
      _Pragma("unroll") for (int nn = 0; nn < 4; ++nn)                                     \
        acc[m][nn] = __builtin_amdgcn_mfma_f32_16x16x32_bf16(AV[m], bf[nn], acc[m][nn], 0, 0, 0); \
    __builtin_amdgcn_s_setprio(0);                                                         \
  } while (0)

#define DN_NT 32
#define DN_ITER(T, SOFF) do {                                          \
    asm volatile("s_waitcnt vmcnt(4)" ::: "memory");                   \
    __builtin_amdgcn_s_barrier(); FENCE;                               \
    short8_t av0_[4], av1_[4];                                         \
    _Pragma("unroll") for (int m = 0; m < 4; ++m) {                    \
      av0_[m] = *(const short8_t*)(pA[m] + (T) * 64);                  \
      av1_[m] = *(const short8_t*)(pA[m] + (T) * 64 + 32);             \
    }                                                                  \
    DN_PHASE(SOFF, 0, av0_);                                           \
    DN_PHASE(SOFF, 1, av1_);                                           \
    FENCE; __builtin_amdgcn_s_barrier(); FENCE;                        \
    if ((T) + 2 < DN_NT) DN_STAGE((T) + 2, SOFF);                      \
  } while (0)

  DN_STAGE(0, 0);
  DN_STAGE(1, 16384);
  for (int t2 = 0; t2 < DN_NT; t2 += 2) { DN_ITER(t2, 0); DN_ITER(t2 + 1, 16384); }
#undef DN_STAGE
#undef DN_PHASE
#undef DN_ITER

  // epilogue: final[t, h] += rw * out  (2 commutative f32 adds per element)
#pragma unroll
  for (int m = 0; m < 4; ++m) {
    int rbase = wr + m * 16 + (lane >> 4) * 4;
#pragma unroll
    for (int j = 0; j < 4; ++j) {
      int r = rbase + j;
      if (r < valid) {
        int t = tokidx[e * TT + row0 + r];
        float w = rww[e * TT + row0 + r];
#pragma unroll
        for (int nn = 0; nn < 4; ++nn) {
          int c = hbase + wc + nn * 16 + fr;
          atomicAdd(&final_out[(size_t)t * HH + c], w * acc[m][nn][j]);
        }
      }
    }
  }
}

extern "C" void kernel_launch(void* const* d_in, const int* in_sizes, int n_in,
                              void* d_out, int out_size, void* d_ws, size_t ws_size,
                              hipStream_t stream) {
  const float* x  = (const float*)d_in[0];   // [T, H]
  const float* gw = (const float*)d_in[1];   // [E, H]
  const float* w1 = (const float*)d_in[2];   // [E, F, H]
  const float* w2 = (const float*)d_in[3];   // [E, H, F]
  const float* w3 = (const float*)d_in[4];   // [E, F, H]

  float* final_out  = (float*)d_out;                       // [T, H]
  float* out_logits = final_out + (size_t)TT * HH;         // [T, E]

  char* ws = (char*)d_ws;
  int*    counts = (int*)(ws + 0);                            // 64 B
  int*    sel01  = (int*)(ws + 1024);                         // 16384
  float2* w01    = (float2*)(ws + 20480);                     // 32768
  int*    tokidx = (int*)(ws + 53248);                        // 131072
  float*  rww    = (float*)(ws + 184320);                     // 131072
  unsigned short* xbf   = (unsigned short*)(ws + 315392);     // 8388608
  unsigned short* w1bf  = (unsigned short*)(ws + 8704000);    // 33554432
  unsigned short* w3bf  = (unsigned short*)(ws + 42258432);   // 33554432
  unsigned short* gated = (unsigned short*)(ws + 75812864);   // 37748736
  const size_t base_end = 113561600;
  bool big = ws_size >= base_end + 33554432;                  // +32MB for w2bf
  unsigned short* w2bf = big ? (unsigned short*)(ws + base_end) : w1bf;

  int nconvblk = (big ? 3 : 2) * NC32;
  front_kernel<<<TT + nconvblk, 256, 0, stream>>>(
      x, gw, w1, w3, w2, out_logits, final_out, xbf, w1bf, w3bf, w2bf,
      sel01, w01);
  build_kernel<<<EE, 256, 0, stream>>>(sel01, w01, counts, tokidx, rww);
  up_gate_kernel<<<dim3(FF / 64, TT / 128, EE), 256, 0, stream>>>(
      xbf, w1bf, w3bf, counts, tokidx, gated);
  if (!big) conv_kernel<<<NC32, 256, 0, stream>>>(w2, w1bf);
  down_kernel<<<dim3(HH / 128, TT / 128, EE), 256, 0, stream>>>(
      gated, w2bf, counts, tokidx, rww, final_out);
}

// Round 11
// 326.471 us; speedup vs baseline: 1.1865x; 1.1865x over previous
//
#include <hip/hip_runtime.h>
#include <hip/hip_bf16.h>

// MoE: B=2,S=2048 -> T=4096 tokens, H=1024, F=2048, E=8, TOPK=2
#define TT 4096
#define HH 1024
#define FF 2048
#define EE 8
#define NC32 2048   // EE*FF*HH / (256*32) conv chunks per weight tensor
#define SLOT 24576  // LDS slot bytes (both GEMMs)

typedef short short8_t __attribute__((ext_vector_type(8)));
typedef float f32x4 __attribute__((ext_vector_type(4)));

__device__ __forceinline__ unsigned short f2b(float f) {
  union { float f; unsigned u; } v; v.f = f;
  return (unsigned short)((v.u + 0x7fffu + ((v.u >> 16) & 1u)) >> 16);  // RNE
}

__device__ __forceinline__ void gload16(const unsigned short* g, void* l) {
  __builtin_amdgcn_global_load_lds(
      (const __attribute__((address_space(1))) void*)g,
      (__attribute__((address_space(3))) void*)l, 16, 0, 0);
}

#define FENCE asm volatile("" ::: "memory")

// Batched-ILP f32->bf16 conv: 8 independent float4 loads in flight per thread.
__device__ __forceinline__ void conv_ilp(const float* __restrict__ src,
                                         unsigned short* __restrict__ dst,
                                         int c, int tid) {
  size_t base = (size_t)c * 8192 + tid * 4;
  float4 v[8];
#pragma unroll
  for (int j = 0; j < 8; ++j)
    v[j] = *reinterpret_cast<const float4*>(src + base + j * 1024);
#pragma unroll
  for (int j = 0; j < 8; ++j) {
    ushort4 b4;
    b4.x = f2b(v[j].x); b4.y = f2b(v[j].y); b4.z = f2b(v[j].z); b4.w = f2b(v[j].w);
    *reinterpret_cast<ushort4*>(dst + base + j * 1024) = b4;
  }
}

// -------- Front: router (atomic-free) + batched-ILP w1/w3[/w2] convs ------------
__global__ __launch_bounds__(256) void front_kernel(
    const float* __restrict__ x, const float* __restrict__ gw,
    const float* __restrict__ w1, const float* __restrict__ w3,
    const float* __restrict__ w2,
    float* __restrict__ out_logits, float* __restrict__ final_out,
    unsigned short* __restrict__ xbf,
    unsigned short* __restrict__ w1bf, unsigned short* __restrict__ w3bf,
    unsigned short* __restrict__ w2bf,
    int* __restrict__ sel01, float2* __restrict__ w01)
{
  int tid = threadIdx.x;
  int b = blockIdx.x;
  if (b >= TT) {
    int cb = b - TT;
    if (cb < NC32)          conv_ilp(w1, w1bf, cb, tid);
    else if (cb < 2 * NC32) conv_ilp(w3, w3bf, cb - NC32, tid);
    else                    conv_ilp(w2, w2bf, cb - 2 * NC32, tid);
    return;
  }
  int t = b;

  __shared__ float xs[HH];
  __shared__ float lg[EE];

  float4 v = reinterpret_cast<const float4*>(x + (size_t)t * HH)[tid];
  xs[tid * 4 + 0] = v.x; xs[tid * 4 + 1] = v.y;
  xs[tid * 4 + 2] = v.z; xs[tid * 4 + 3] = v.w;
  ushort4 b4;
  b4.x = f2b(v.x); b4.y = f2b(v.y); b4.z = f2b(v.z); b4.w = f2b(v.w);
  reinterpret_cast<ushort4*>(xbf + (size_t)t * HH)[tid] = b4;
  float4 z4; z4.x = z4.y = z4.z = z4.w = 0.f;
  reinterpret_cast<float4*>(final_out + (size_t)t * HH)[tid] = z4;
  __syncthreads();

  int lane = tid & 63, wv = tid >> 6;
  for (int e = wv; e < EE; e += 4) {
    float s = 0.f;
    const float* g = gw + (size_t)e * HH;
#pragma unroll
    for (int j = 0; j < HH / 64; ++j) s += xs[lane + j * 64] * g[lane + j * 64];
#pragma unroll
    for (int off = 32; off > 0; off >>= 1) s += __shfl_down(s, off);
    if (lane == 0) lg[e] = s;
  }
  __syncthreads();

  if (tid < 8) out_logits[(size_t)t * EE + tid] = lg[tid];
  if (tid == 0) {
    float l[EE];
#pragma unroll
    for (int e = 0; e < EE; ++e) l[e] = lg[e];
    int e0 = 0;
#pragma unroll
    for (int e = 1; e < EE; ++e) if (l[e] > l[e0]) e0 = e;
    int e1 = -1;
#pragma unroll
    for (int e = 0; e < EE; ++e) if (e != e0 && (e1 < 0 || l[e] > l[e1])) e1 = e;
    float p1 = expf(l[e1] - l[e0]);
    float w0 = 1.f / (1.f + p1);
    float w1v = p1 * w0;
    sel01[t] = e0 | (e1 << 8);
    w01[t] = make_float2(w0, w1v);
  }
}

// -------- Build: per-expert compacted token lists, atomic-free, deterministic ----
__global__ __launch_bounds__(256) void build_kernel(
    const int* __restrict__ sel01, const float2* __restrict__ w01,
    int* __restrict__ counts, int* __restrict__ tokidx, float* __restrict__ rww)
{
  int e = blockIdx.x;
  int tid = threadIdx.x, lane = tid & 63, wv = tid >> 6;
  __shared__ int wsum[4];
  int base = 0;
  for (int t0 = 0; t0 < TT; t0 += 256) {
    int t = t0 + tid;
    int s = sel01[t];
    int e0 = s & 255, e1 = (s >> 8) & 255;
    bool hit = (e0 == e) || (e1 == e);
    float w = 0.f;
    if (hit) { float2 ww = w01[t]; w = (e0 == e) ? ww.x : ww.y; }
    unsigned long long m = __ballot(hit);
    int wpre = __popcll(m & ((1ull << lane) - 1));
    if (lane == 63) wsum[wv] = wpre + (hit ? 1 : 0);
    __syncthreads();
    int wbase = base;
    for (int q = 0; q < wv; ++q) wbase += wsum[q];
    if (hit) {
      int pos = wbase + wpre;
      tokidx[e * TT + pos] = t;
      rww[e * TT + pos] = w;
    }
    base += wsum[0] + wsum[1] + wsum[2] + wsum[3];
    __syncthreads();
  }
  if (tid == 0) counts[e] = base;
}

// -------- Standalone conv for w2 (fallback when ws too small: after up_gate) ----
__global__ __launch_bounds__(256) void conv_kernel(
    const float* __restrict__ src, unsigned short* __restrict__ dst)
{
  conv_ilp(src, dst, blockIdx.x, threadIdx.x);
}

// -------- Up-proj + gate: tile 128x128 dual-GEMM, BK=32, 2-slot counted-vmcnt ---
// Slot (bytes): A[0,8192) 128x32, B1[8192,16384) 128x32, B3[16384,24576) 128x32.
// Rows are 64B; bank-free via block-XOR kq' = kq ^ ((row>>1)&3), applied on the
// pre-swizzled global SOURCE (LDS dest linear) and on the ds_read address.
__global__ __launch_bounds__(256) void up_gate_kernel(
    const unsigned short* __restrict__ xbf,
    const unsigned short* __restrict__ w1bf, const unsigned short* __restrict__ w3bf,
    const int* __restrict__ counts, const int* __restrict__ tokidx,
    unsigned short* __restrict__ gated)
{
  int e = blockIdx.z;
  int n = counts[e];
  int row0 = blockIdx.y * 128;
  if (row0 >= n) return;
  int fbase = blockIdx.x * 128;

  int pe = 0;
  for (int q = 0; q < e; ++q) pe += (counts[q] + 127) & ~127;

  __shared__ __align__(16) char lds[2 * SLOT];   // 48 KB

  int tid = threadIdx.x;
  int lane = tid & 63, wv = tid >> 6;
  int sr = tid >> 2;                       // staging row 0..63
  int sb = (tid & 3) ^ ((tid >> 3) & 3);   // swizzled source 16B-block (f(r)=(r>>1)&3)

  // gathered A rows (clamped pads duplicate a valid token; outputs discarded)
  int r0 = min(row0 + sr, n - 1);
  int r1 = min(row0 + 64 + sr, n - 1);
  const unsigned short* ga0 = xbf + (size_t)tokidx[e * TT + r0] * HH + sb * 8;
  const unsigned short* ga1 = xbf + (size_t)tokidx[e * TT + r1] * HH + sb * 8;
  const unsigned short* gb1a = w1bf + ((size_t)e * FF + fbase + sr) * HH + sb * 8;
  const unsigned short* gb1b = gb1a + (size_t)64 * HH;
  const unsigned short* gb3a = w3bf + ((size_t)e * FF + fbase + sr) * HH + sb * 8;
  const unsigned short* gb3b = gb3a + (size_t)64 * HH;

  int wr = (wv >> 1) * 64, wc = (wv & 1) * 64;
  int fr = lane & 15, kq = lane >> 4;

  // loop-invariant swizzled fragment offsets
  int offA[4], offB[4];
#pragma unroll
  for (int m = 0; m < 4; ++m) {
    int r = wr + m * 16 + fr;
    offA[m] = r * 64 + ((kq ^ ((r >> 1) & 3)) << 4);
  }
#pragma unroll
  for (int nn = 0; nn < 4; ++nn) {
    int r = wc + nn * 16 + fr;
    offB[nn] = r * 64 + ((kq ^ ((r >> 1) & 3)) << 4);
  }

  f32x4 acc1[4][4], acc3[4][4];
#pragma unroll
  for (int m = 0; m < 4; ++m)
#pragma unroll
    for (int nn = 0; nn < 4; ++nn) { acc1[m][nn] = (f32x4)0.f; acc3[m][nn] = (f32x4)0.f; }

#define UG_STAGE(T, SOFF) do {                                  \
    gload16(ga0  + (T) * 32, lds + (SOFF) +         wv * 1024); \
    gload16(ga1  + (T) * 32, lds + (SOFF) +  4096 + wv * 1024); \
    gload16(gb1a + (T) * 32, lds + (SOFF) +  8192 + wv * 1024); \
    gload16(gb1b + (T) * 32, lds + (SOFF) + 12288 + wv * 1024); \
    gload16(gb3a + (T) * 32, lds + (SOFF) + 16384 + wv * 1024); \
    gload16(gb3b + (T) * 32, lds + (SOFF) + 20480 + wv * 1024); } while (0)

#define UG_NT 32
#define UG_ITER(T, SOFF) do {                                                      \
    if ((T) < UG_NT - 1) asm volatile("s_waitcnt vmcnt(6)" ::: "memory");          \
    else                 asm volatile("s_waitcnt vmcnt(0)" ::: "memory");          \
    __builtin_amdgcn_s_barrier(); FENCE;                                           \
    short8_t a_[4], b1_[4], b3_[4];                                                \
    _Pragma("unroll") for (int m = 0; m < 4; ++m)                                  \
      a_[m] = *(const short8_t*)(lds + (SOFF) + offA[m]);                          \
    _Pragma("unroll") for (int nn = 0; nn < 4; ++nn) {                             \
      b1_[nn] = *(const short8_t*)(lds + (SOFF) +  8192 + offB[nn]);               \
      b3_[nn] = *(const short8_t*)(lds + (SOFF) + 16384 + offB[nn]);               \
    }                                                                              \
    __builtin_amdgcn_s_setprio(1);                                                 \
    _Pragma("unroll") for (int m = 0; m < 4; ++m)                                  \
      _Pragma("unroll") for (int nn = 0; nn < 4; ++nn) {                           \
        acc1[m][nn] = __builtin_amdgcn_mfma_f32_16x16x32_bf16(a_[m], b1_[nn], acc1[m][nn], 0, 0, 0); \
        acc3[m][nn] = __builtin_amdgcn_mfma_f32_16x16x32_bf16(a_[m], b3_[nn], acc3[m][nn], 0, 0, 0); \
      }                                                                            \
    __builtin_amdgcn_s_setprio(0);                                                 \
    FENCE; __builtin_amdgcn_s_barrier(); FENCE;                                    \
    if ((T) + 2 < UG_NT) UG_STAGE((T) + 2, SOFF);                                  \
  } while (0)

  UG_STAGE(0, 0);
  UG_STAGE(1, SLOT);
  for (int t2 = 0; t2 < UG_NT; t2 += 2) { UG_ITER(t2, 0); UG_ITER(t2 + 1, SLOT); }
#undef UG_STAGE
#undef UG_ITER

  // epilogue: gated = silu(h1)*h3 -> bf16
  size_t gbase = ((size_t)pe + row0) * FF + fbase;
#pragma unroll
  for (int m = 0; m < 4; ++m) {
#pragma unroll
    for (int nn = 0; nn < 4; ++nn) {
      f32x4 h1v = acc1[m][nn], h3v = acc3[m][nn];
#pragma unroll
      for (int j = 0; j < 4; ++j) {
        float z = h1v[j];
        float val = (z / (1.f + expf(-z))) * h3v[j];
        int r = wr + m * 16 + kq * 4 + j;
        int c = wc + nn * 16 + fr;
        gated[gbase + (size_t)r * FF + c] = f2b(val);
      }
    }
  }
}

// -------- Down-proj + scatter: tile 128x256, BK=32, 2-slot counted-vmcnt --------
// Slot (bytes): A[0,8192) 128x32 (gated), B[8192,24576) 256x32 (w2 rows).
__global__ __launch_bounds__(256) void down_kernel(
    const unsigned short* __restrict__ gated,
    const unsigned short* __restrict__ w2bf,
    const int* __restrict__ counts, const int* __restrict__ tokidx,
    const float* __restrict__ rww,
    float* __restrict__ final_out)
{
  int e = blockIdx.z;
  int n = counts[e];
  int row0 = blockIdx.y * 128;
  if (row0 >= n) return;
  int hbase = blockIdx.x * 256;
  int valid = min(128, n - row0);

  int pe = 0;
  for (int q = 0; q < e; ++q) pe += (counts[q] + 127) & ~127;

  __shared__ __align__(16) char lds[2 * SLOT];   // 48 KB

  int tid = threadIdx.x;
  int lane = tid & 63, wv = tid >> 6;
  int sr = tid >> 2;
  int sb = (tid & 3) ^ ((tid >> 3) & 3);

  const unsigned short* ga0 = gated + ((size_t)pe + row0 + sr) * FF + sb * 8;
  const unsigned short* ga1 = ga0 + (size_t)64 * FF;
  const unsigned short* gb0 = w2bf + ((size_t)e * HH + hbase + sr) * FF + sb * 8;
  const unsigned short* gb1_ = gb0 + (size_t)64 * FF;
  const unsigned short* gb2_ = gb0 + (size_t)128 * FF;
  const unsigned short* gb3_ = gb0 + (size_t)192 * FF;

  int wr = (wv >> 1) * 64, wc = (wv & 1) * 128;
  int fr = lane & 15, kq = lane >> 4;

  int offA[4], offB[8];
#pragma unroll
  for (int m = 0; m < 4; ++m) {
    int r = wr + m * 16 + fr;
    offA[m] = r * 64 + ((kq ^ ((r >> 1) & 3)) << 4);
  }
#pragma unroll
  for (int nn = 0; nn < 8; ++nn) {
    int r = wc + nn * 16 + fr;
    offB[nn] = r * 64 + ((kq ^ ((r >> 1) & 3)) << 4);
  }

  f32x4 acc[4][8];
#pragma unroll
  for (int m = 0; m < 4; ++m)
#pragma unroll
    for (int nn = 0; nn < 8; ++nn) acc[m][nn] = (f32x4)0.f;

#define DN_STAGE(T, SOFF) do {                                  \
    gload16(ga0  + (T) * 32, lds + (SOFF) +         wv * 1024); \
    gload16(ga1  + (T) * 32, lds + (SOFF) +  4096 + wv * 1024); \
    gload16(gb0  + (T) * 32, lds + (SOFF) +  8192 + wv * 1024); \
    gload16(gb1_ + (T) * 32, lds + (SOFF) + 12288 + wv * 1024); \
    gload16(gb2_ + (T) * 32, lds + (SOFF) + 16384 + wv * 1024); \
    gload16(gb3_ + (T) * 32, lds + (SOFF) + 20480 + wv * 1024); } while (0)

#define DN_NT 64
#define DN_ITER(T, SOFF) do {                                                      \
    if ((T) < DN_NT - 1) asm volatile("s_waitcnt vmcnt(6)" ::: "memory");          \
    else                 asm volatile("s_waitcnt vmcnt(0)" ::: "memory");          \
    __builtin_amdgcn_s_barrier(); FENCE;                                           \
    short8_t a_[4], b_[8];                                                         \
    _Pragma("unroll") for (int m = 0; m < 4; ++m)                                  \
      a_[m] = *(const short8_t*)(lds + (SOFF) + offA[m]);                          \
    _Pragma("unroll") for (int nn = 0; nn < 8; ++nn)                               \
      b_[nn] = *(const short8_t*)(lds + (SOFF) + 8192 + offB[nn]);                 \
    __builtin_amdgcn_s_setprio(1);                                                 \
    _Pragma("unroll") for (int m = 0; m < 4; ++m)                                  \
      _Pragma("unroll") for (int nn = 0; nn < 8; ++nn)                             \
        acc[m][nn] = __builtin_amdgcn_mfma_f32_16x16x32_bf16(a_[m], b_[nn], acc[m][nn], 0, 0, 0); \
    __builtin_amdgcn_s_setprio(0);                                                 \
    FENCE; __builtin_amdgcn_s_barrier(); FENCE;                                    \
    if ((T) + 2 < DN_NT) DN_STAGE((T) + 2, SOFF);                                  \
  } while (0)

  DN_STAGE(0, 0);
  DN_STAGE(1, SLOT);
  for (int t2 = 0; t2 < DN_NT; t2 += 2) { DN_ITER(t2, 0); DN_ITER(t2 + 1, SLOT); }
#undef DN_STAGE
#undef DN_ITER

  // epilogue: final[t, h] += rw * out  (2 commutative f32 adds per element)
#pragma unroll
  for (int m = 0; m < 4; ++m) {
    int rbase = wr + m * 16 + kq * 4;
#pragma unroll
    for (int j = 0; j < 4; ++j) {
      int r = rbase + j;
      if (r < valid) {
        int t = tokidx[e * TT + row0 + r];
        float w = rww[e * TT + row0 + r];
#pragma unroll
        for (int nn = 0; nn < 8; ++nn) {
          int c = hbase + wc + nn * 16 + fr;
          atomicAdd(&final_out[(size_t)t * HH + c], w * acc[m][nn][j]);
        }
      }
    }
  }
}

extern "C" void kernel_launch(void* const* d_in, const int* in_sizes, int n_in,
                              void* d_out, int out_size, void* d_ws, size_t ws_size,
                              hipStream_t stream) {
  const float* x  = (const float*)d_in[0];   // [T, H]
  const float* gw = (const float*)d_in[1];   // [E, H]
  const float* w1 = (const float*)d_in[2];   // [E, F, H]
  const float* w2 = (const float*)d_in[3];   // [E, H, F]
  const float* w3 = (const float*)d_in[4];   // [E, F, H]

  float* final_out  = (float*)d_out;                       // [T, H]
  float* out_logits = final_out + (size_t)TT * HH;         // [T, E]

  char* ws = (char*)d_ws;
  int*    counts = (int*)(ws + 0);                            // 64 B
  int*    sel01  = (int*)(ws + 1024);                         // 16384
  float2* w01    = (float2*)(ws + 20480);                     // 32768
  int*    tokidx = (int*)(ws + 53248);                        // 131072
  float*  rww    = (float*)(ws + 184320);                     // 131072
  unsigned short* xbf   = (unsigned short*)(ws + 315392);     // 8388608
  unsigned short* w1bf  = (unsigned short*)(ws + 8704000);    // 33554432
  unsigned short* w3bf  = (unsigned short*)(ws + 42258432);   // 33554432
  unsigned short* gated = (unsigned short*)(ws + 75812864);   // 37748736
  const size_t base_end = 113561600;
  bool big = ws_size >= base_end + 33554432;                  // +32MB for w2bf
  unsigned short* w2bf = big ? (unsigned short*)(ws + base_end) : w1bf;

  int nconvblk = (big ? 3 : 2) * NC32;
  front_kernel<<<TT + nconvblk, 256, 0, stream>>>(
      x, gw, w1, w3, w2, out_logits, final_out, xbf, w1bf, w3bf, w2bf,
      sel01, w01);
  build_kernel<<<EE, 256, 0, stream>>>(sel01, w01, counts, tokidx, rww);
  up_gate_kernel<<<dim3(FF / 128, TT / 128, EE), 256, 0, stream>>>(
      xbf, w1bf, w3bf, counts, tokidx, gated);
  if (!big) conv_kernel<<<NC32, 256, 0, stream>>>(w2, w1bf);
  down_kernel<<<dim3(HH / 256, TT / 128, EE), 256, 0, stream>>>(
      gated, w2bf, counts, tokidx, rww, final_out);
}

// Round 12
// 269.293 us; speedup vs baseline: 1.4385x; 1.2123x over previous
//
#include <hip/hip_runtime.h>
#include <hip/hip_bf16.h>

// MoE: B=2,S=2048 -> T=4096 tokens, H=1024, F=2048, E=8, TOPK=2
#define TT 4096
#define HH 1024
#define FF 2048
#define EE 8
#define NC32 2048   // EE*FF*HH / (256*32) conv chunks per weight tensor
#define LDSU 32768  // LDS slot stride (bytes)

typedef short short8_t __attribute__((ext_vector_type(8)));
typedef float f32x4 __attribute__((ext_vector_type(4)));
typedef float f32x16 __attribute__((ext_vector_type(16)));

__device__ __forceinline__ unsigned short f2b(float f) {
  union { float f; unsigned u; } v; v.f = f;
  return (unsigned short)((v.u + 0x7fffu + ((v.u >> 16) & 1u)) >> 16);  // RNE
}

__device__ __forceinline__ void gload16(const unsigned short* g, void* l) {
  __builtin_amdgcn_global_load_lds(
      (const __attribute__((address_space(1))) void*)g,
      (__attribute__((address_space(3))) void*)l, 16, 0, 0);
}

#define FENCE asm volatile("" ::: "memory")

// Batched-ILP f32->bf16 conv: 8 independent float4 loads in flight per thread.
__device__ __forceinline__ void conv_ilp(const float* __restrict__ src,
                                         unsigned short* __restrict__ dst,
                                         int c, int tid) {
  size_t base = (size_t)c * 8192 + tid * 4;
  float4 v[8];
#pragma unroll
  for (int j = 0; j < 8; ++j)
    v[j] = *reinterpret_cast<const float4*>(src + base + j * 1024);
#pragma unroll
  for (int j = 0; j < 8; ++j) {
    ushort4 b4;
    b4.x = f2b(v[j].x); b4.y = f2b(v[j].y); b4.z = f2b(v[j].z); b4.w = f2b(v[j].w);
    *reinterpret_cast<ushort4*>(dst + base + j * 1024) = b4;
  }
}

// -------- Front: router (atomic-free) + batched-ILP w1/w3[/w2] convs ------------
__global__ __launch_bounds__(256) void front_kernel(
    const float* __restrict__ x, const float* __restrict__ gw,
    const float* __restrict__ w1, const float* __restrict__ w3,
    const float* __restrict__ w2,
    float* __restrict__ out_logits, float* __restrict__ final_out,
    unsigned short* __restrict__ xbf,
    unsigned short* __restrict__ w1bf, unsigned short* __restrict__ w3bf,
    unsigned short* __restrict__ w2bf,
    int* __restrict__ sel01, float2* __restrict__ w01)
{
  int tid = threadIdx.x;
  int b = blockIdx.x;
  if (b >= TT) {
    int cb = b - TT;
    if (cb < NC32)          conv_ilp(w1, w1bf, cb, tid);
    else if (cb < 2 * NC32) conv_ilp(w3, w3bf, cb - NC32, tid);
    else                    conv_ilp(w2, w2bf, cb - 2 * NC32, tid);
    return;
  }
  int t = b;

  __shared__ float xs[HH];
  __shared__ float lg[EE];

  float4 v = reinterpret_cast<const float4*>(x + (size_t)t * HH)[tid];
  xs[tid * 4 + 0] = v.x; xs[tid * 4 + 1] = v.y;
  xs[tid * 4 + 2] = v.z; xs[tid * 4 + 3] = v.w;
  ushort4 b4;
  b4.x = f2b(v.x); b4.y = f2b(v.y); b4.z = f2b(v.z); b4.w = f2b(v.w);
  reinterpret_cast<ushort4*>(xbf + (size_t)t * HH)[tid] = b4;
  float4 z4; z4.x = z4.y = z4.z = z4.w = 0.f;
  reinterpret_cast<float4*>(final_out + (size_t)t * HH)[tid] = z4;
  __syncthreads();

  int lane = tid & 63, wv = tid >> 6;
  for (int e = wv; e < EE; e += 4) {
    float s = 0.f;
    const float* g = gw + (size_t)e * HH;
#pragma unroll
    for (int j = 0; j < HH / 64; ++j) s += xs[lane + j * 64] * g[lane + j * 64];
#pragma unroll
    for (int off = 32; off > 0; off >>= 1) s += __shfl_down(s, off);
    if (lane == 0) lg[e] = s;
  }
  __syncthreads();

  if (tid < 8) out_logits[(size_t)t * EE + tid] = lg[tid];
  if (tid == 0) {
    float l[EE];
#pragma unroll
    for (int e = 0; e < EE; ++e) l[e] = lg[e];
    int e0 = 0;
#pragma unroll
    for (int e = 1; e < EE; ++e) if (l[e] > l[e0]) e0 = e;
    int e1 = -1;
#pragma unroll
    for (int e = 0; e < EE; ++e) if (e != e0 && (e1 < 0 || l[e] > l[e1])) e1 = e;
    float p1 = expf(l[e1] - l[e0]);
    float w0 = 1.f / (1.f + p1);
    float w1v = p1 * w0;
    sel01[t] = e0 | (e1 << 8);
    w01[t] = make_float2(w0, w1v);
  }
}

// -------- Build: per-expert compacted token lists, atomic-free, deterministic ----
__global__ __launch_bounds__(256) void build_kernel(
    const int* __restrict__ sel01, const float2* __restrict__ w01,
    int* __restrict__ counts, int* __restrict__ tokidx, float* __restrict__ rww)
{
  int e = blockIdx.x;
  int tid = threadIdx.x, lane = tid & 63, wv = tid >> 6;
  __shared__ int wsum[4];
  int base = 0;
  for (int t0 = 0; t0 < TT; t0 += 256) {
    int t = t0 + tid;
    int s = sel01[t];
    int e0 = s & 255, e1 = (s >> 8) & 255;
    bool hit = (e0 == e) || (e1 == e);
    float w = 0.f;
    if (hit) { float2 ww = w01[t]; w = (e0 == e) ? ww.x : ww.y; }
    unsigned long long m = __ballot(hit);
    int wpre = __popcll(m & ((1ull << lane) - 1));
    if (lane == 63) wsum[wv] = wpre + (hit ? 1 : 0);
    __syncthreads();
    int wbase = base;
    for (int q = 0; q < wv; ++q) wbase += wsum[q];
    if (hit) {
      int pos = wbase + wpre;
      tokidx[e * TT + pos] = t;
      rww[e * TT + pos] = w;
    }
    base += wsum[0] + wsum[1] + wsum[2] + wsum[3];
    __syncthreads();
  }
  if (tid == 0) counts[e] = base;
}

// -------- Standalone conv for w2 (fallback when ws too small: after up_gate) ----
__global__ __launch_bounds__(256) void conv_kernel(
    const float* __restrict__ src, unsigned short* __restrict__ dst)
{
  conv_ilp(src, dst, blockIdx.x, threadIdx.x);
}

// -------- Up-proj + gate: BK=64, 2-slot counted-vmcnt, 32x32x16 MFMA ------------
// Slot layout (bytes): A[0,16384) 128x64, B1[16384,24576) 64x64, B3[24576,32768).
// Swizzle: 16B-block index ^= (row & 7); pre-swizzled global SOURCE at stage time
// (LDS dest linear, per global_load_lds semantics) + swizzled ds_read address.
__global__ __launch_bounds__(256) void up_gate_kernel(
    const unsigned short* __restrict__ xbf,
    const unsigned short* __restrict__ w1bf, const unsigned short* __restrict__ w3bf,
    const int* __restrict__ counts, const int* __restrict__ tokidx,
    unsigned short* __restrict__ gated)
{
  int e = blockIdx.z;
  int n = counts[e];
  int row0 = blockIdx.y * 128;
  if (row0 >= n) return;
  int fbase = blockIdx.x * 64;

  int pe = 0;
  for (int q = 0; q < e; ++q) pe += (counts[q] + 127) & ~127;

  __shared__ __align__(16) char lds[2 * LDSU];   // 64 KB

  int tid = threadIdx.x;
  int lane = tid & 63, wv = tid >> 6;
  int sb = (tid & 7) ^ ((tid >> 3) & 7);   // swizzled source 16B-block

  const unsigned short* ga[4];
#pragma unroll
  for (int j = 0; j < 4; ++j) {
    int r = min(row0 + (tid >> 3) + 32 * j, n - 1);
    ga[j] = xbf + (size_t)tokidx[e * TT + r] * HH + sb * 8;
  }
  const unsigned short* gb1[2];
  const unsigned short* gb3[2];
#pragma unroll
  for (int j = 0; j < 2; ++j) {
    size_t rw_ = (size_t)e * FF + fbase + (tid >> 3) + 32 * j;
    gb1[j] = w1bf + rw_ * HH + sb * 8;
    gb3[j] = w3bf + rw_ * HH + sb * 8;
  }

  int wr = (wv >> 1) * 64, wc32 = (wv & 1) * 32;
  int l31 = lane & 31, kq = lane >> 5, l7 = lane & 7;

  // loop-invariant row-byte offsets (swizzle term added per k-step)
  int offA[2];
#pragma unroll
  for (int m = 0; m < 2; ++m) offA[m] = (wr + m * 32 + l31) * 128;
  int offB1 = 16384 + (wc32 + l31) * 128;
  int offB3 = 24576 + (wc32 + l31) * 128;

  f32x16 acc1[2], acc3[2];
#pragma unroll
  for (int m = 0; m < 2; ++m) { acc1[m] = (f32x16)0.f; acc3[m] = (f32x16)0.f; }

#define UG_STAGE(T, SOFF) do {                                                     \
    _Pragma("unroll") for (int j = 0; j < 4; ++j)                                  \
      gload16(ga[j] + (T) * 64, lds + (SOFF) + j * 4096 + wv * 1024);              \
    _Pragma("unroll") for (int j = 0; j < 2; ++j) {                                \
      gload16(gb1[j] + (T) * 64, lds + (SOFF) + 16384 + j * 4096 + wv * 1024);     \
      gload16(gb3[j] + (T) * 64, lds + (SOFF) + 24576 + j * 4096 + wv * 1024);     \
    } } while (0)

// phase KS covers k-steps 2KS, 2KS+1 (each K=16); block idx = kstep*2 + kq
#define UG_PHASE(SOFF, KS) do {                                                             \
    int swz0 = (((KS) * 4 + 0 + kq) ^ l7) * 16;                                             \
    int swz1 = (((KS) * 4 + 2 + kq) ^ l7) * 16;                                             \
    short8_t a0_[2], a1_[2];                                                                \
    _Pragma("unroll") for (int m = 0; m < 2; ++m) {                                         \
      a0_[m] = *(const short8_t*)(lds + (SOFF) + offA[m] + swz0);                           \
      a1_[m] = *(const short8_t*)(lds + (SOFF) + offA[m] + swz1);                           \
    }                                                                                       \
    short8_t b1k0 = *(const short8_t*)(lds + (SOFF) + offB1 + swz0);                        \
    short8_t b1k1 = *(const short8_t*)(lds + (SOFF) + offB1 + swz1);                        \
    short8_t b3k0 = *(const short8_t*)(lds + (SOFF) + offB3 + swz0);                        \
    short8_t b3k1 = *(const short8_t*)(lds + (SOFF) + offB3 + swz1);                        \
    __builtin_amdgcn_s_setprio(1);                                                          \
    _Pragma("unroll") for (int m = 0; m < 2; ++m) {                                         \
      acc1[m] = __builtin_amdgcn_mfma_f32_32x32x16_bf16(a0_[m], b1k0, acc1[m], 0, 0, 0);    \
      acc1[m] = __builtin_amdgcn_mfma_f32_32x32x16_bf16(a1_[m], b1k1, acc1[m], 0, 0, 0);    \
      acc3[m] = __builtin_amdgcn_mfma_f32_32x32x16_bf16(a0_[m], b3k0, acc3[m], 0, 0, 0);    \
      acc3[m] = __builtin_amdgcn_mfma_f32_32x32x16_bf16(a1_[m], b3k1, acc3[m], 0, 0, 0);    \
    }                                                                                       \
    __builtin_amdgcn_s_setprio(0);                                                          \
  } while (0)

#define UG_NT 16
#define UG_ITER(T, SOFF) do {                                          \
    if ((T) < UG_NT - 1) asm volatile("s_waitcnt vmcnt(8)" ::: "memory"); \
    else                 asm volatile("s_waitcnt vmcnt(0)" ::: "memory"); \
    __builtin_amdgcn_s_barrier(); FENCE;                               \
    UG_PHASE(SOFF, 0);                                                 \
    FENCE; __builtin_amdgcn_s_barrier(); FENCE;                        \
    UG_PHASE(SOFF, 1);                                                 \
    FENCE; __builtin_amdgcn_s_barrier(); FENCE;                        \
    if ((T) + 2 < UG_NT) UG_STAGE((T) + 2, SOFF);                      \
  } while (0)

  UG_STAGE(0, 0);
  UG_STAGE(1, LDSU);
  for (int t2 = 0; t2 < UG_NT; t2 += 2) { UG_ITER(t2, 0); UG_ITER(t2 + 1, LDSU); }
#undef UG_STAGE
#undef UG_PHASE
#undef UG_ITER

  // epilogue: gated = silu(h1)*h3 -> bf16.  32x32 C-layout:
  // col = lane&31, row = (reg&3) + 8*(reg>>2) + 4*(lane>>5)
  size_t gbase = ((size_t)pe + row0) * FF + fbase;
#pragma unroll
  for (int m = 0; m < 2; ++m) {
#pragma unroll
    for (int reg = 0; reg < 16; ++reg) {
      float z = acc1[m][reg];
      float val = (z / (1.f + expf(-z))) * acc3[m][reg];
      int r = wr + m * 32 + (reg & 3) + 8 * (reg >> 2) + 4 * kq;
      int c = wc32 + l31;
      gated[gbase + (size_t)r * FF + c] = f2b(val);
    }
  }
}

// -------- Down-proj + scatter: BK=64, 2-slot counted-vmcnt, 32x32x16 MFMA -------
// Slot layout (bytes): A[0,16384) 128x64, B[16384,32768) 128x64.
__global__ __launch_bounds__(256) void down_kernel(
    const unsigned short* __restrict__ gated,
    const unsigned short* __restrict__ w2bf,
    const int* __restrict__ counts, const int* __restrict__ tokidx,
    const float* __restrict__ rww,
    float* __restrict__ final_out)
{
  int e = blockIdx.z;
  int n = counts[e];
  int row0 = blockIdx.y * 128;
  if (row0 >= n) return;
  int hbase = blockIdx.x * 128;
  int valid = min(128, n - row0);

  int pe = 0;
  for (int q = 0; q < e; ++q) pe += (counts[q] + 127) & ~127;

  __shared__ __align__(16) char lds[2 * LDSU];   // 64 KB

  int tid = threadIdx.x;
  int lane = tid & 63, wv = tid >> 6;
  int sb = (tid & 7) ^ ((tid >> 3) & 7);

  const unsigned short* ga[4];
  const unsigned short* gb[4];
#pragma unroll
  for (int j = 0; j < 4; ++j) {
    ga[j] = gated + ((size_t)pe + row0 + (tid >> 3) + 32 * j) * FF + sb * 8;
    gb[j] = w2bf + ((size_t)e * HH + hbase + (tid >> 3) + 32 * j) * FF + sb * 8;
  }

  int wr = (wv >> 1) * 64, wc = (wv & 1) * 64;
  int l31 = lane & 31, kq = lane >> 5, l7 = lane & 7;

  int offA[2], offB[2];
#pragma unroll
  for (int m = 0; m < 2; ++m) offA[m] = (wr + m * 32 + l31) * 128;
#pragma unroll
  for (int nn = 0; nn < 2; ++nn) offB[nn] = 16384 + (wc + nn * 32 + l31) * 128;

  f32x16 acc[2][2];
#pragma unroll
  for (int m = 0; m < 2; ++m)
#pragma unroll
    for (int nn = 0; nn < 2; ++nn) acc[m][nn] = (f32x16)0.f;

#define DN_STAGE(T, SOFF) do {                                                   \
    _Pragma("unroll") for (int j = 0; j < 4; ++j) {                              \
      gload16(ga[j] + (T) * 64, lds + (SOFF) + j * 4096 + wv * 1024);            \
      gload16(gb[j] + (T) * 64, lds + (SOFF) + 16384 + j * 4096 + wv * 1024);    \
    } } while (0)

#define DN_PHASE(SOFF, KS) do {                                                            \
    int swz0 = (((KS) * 4 + 0 + kq) ^ l7) * 16;                                            \
    int swz1 = (((KS) * 4 + 2 + kq) ^ l7) * 16;                                            \
    short8_t a0_[2], a1_[2], b0_[2], b1_[2];                                               \
    _Pragma("unroll") for (int m = 0; m < 2; ++m) {                                        \
      a0_[m] = *(const short8_t*)(lds + (SOFF) + offA[m] + swz0);                          \
      a1_[m] = *(const short8_t*)(lds + (SOFF) + offA[m] + swz1);                          \
    }                                                                                      \
    _Pragma("unroll") for (int nn = 0; nn < 2; ++nn) {                                     \
      b0_[nn] = *(const short8_t*)(lds + (SOFF) + offB[nn] + swz0);                        \
      b1_[nn] = *(const short8_t*)(lds + (SOFF) + offB[nn] + swz1);                        \
    }                                                                                      \
    __builtin_amdgcn_s_setprio(1);                                                         \
    _Pragma("unroll") for (int m = 0; m < 2; ++m)                                          \
      _Pragma("unroll") for (int nn = 0; nn < 2; ++nn) {                                   \
        acc[m][nn] = __builtin_amdgcn_mfma_f32_32x32x16_bf16(a0_[m], b0_[nn], acc[m][nn], 0, 0, 0); \
        acc[m][nn] = __builtin_amdgcn_mfma_f32_32x32x16_bf16(a1_[m], b1_[nn], acc[m][nn], 0, 0, 0); \
      }                                                                                    \
    __builtin_amdgcn_s_setprio(0);                                                         \
  } while (0)

#define DN_NT 32
#define DN_ITER(T, SOFF) do {                                          \
    if ((T) < DN_NT - 1) asm volatile("s_waitcnt vmcnt(8)" ::: "memory"); \
    else                 asm volatile("s_waitcnt vmcnt(0)" ::: "memory"); \
    __builtin_amdgcn_s_barrier(); FENCE;                               \
    DN_PHASE(SOFF, 0);                                                 \
    FENCE; __builtin_amdgcn_s_barrier(); FENCE;                        \
    DN_PHASE(SOFF, 1);                                                 \
    FENCE; __builtin_amdgcn_s_barrier(); FENCE;                        \
    if ((T) + 2 < DN_NT) DN_STAGE((T) + 2, SOFF);                      \
  } while (0)

  DN_STAGE(0, 0);
  DN_STAGE(1, LDSU);
  for (int t2 = 0; t2 < DN_NT; t2 += 2) { DN_ITER(t2, 0); DN_ITER(t2 + 1, LDSU); }
#undef DN_STAGE
#undef DN_PHASE
#undef DN_ITER

  // epilogue: final[t, h] += rw * out  (2 commutative f32 adds per element)
  // 32x32 C-layout: col = lane&31, row = (reg&3)+8*(reg>>2)+4*(lane>>5)
#pragma unroll
  for (int m = 0; m < 2; ++m) {
#pragma unroll
    for (int reg = 0; reg < 16; ++reg) {
      int r = wr + m * 32 + (reg & 3) + 8 * (reg >> 2) + 4 * kq;
      if (r < valid) {
        int t = tokidx[e * TT + row0 + r];
        float w = rww[e * TT + row0 + r];
#pragma unroll
        for (int nn = 0; nn < 2; ++nn) {
          int c = hbase + wc + nn * 32 + l31;
          atomicAdd(&final_out[(size_t)t * HH + c], w * acc[m][nn][reg]);
        }
      }
    }
  }
}

extern "C" void kernel_launch(void* const* d_in, const int* in_sizes, int n_in,
                              void* d_out, int out_size, void* d_ws, size_t ws_size,
                              hipStream_t stream) {
  const float* x  = (const float*)d_in[0];   // [T, H]
  const float* gw = (const float*)d_in[1];   // [E, H]
  const float* w1 = (const float*)d_in[2];   // [E, F, H]
  const float* w2 = (const float*)d_in[3];   // [E, H, F]
  const float* w3 = (const float*)d_in[4];   // [E, F, H]

  float* final_out  = (float*)d_out;                       // [T, H]
  float* out_logits = final_out + (size_t)TT * HH;         // [T, E]

  char* ws = (char*)d_ws;
  int*    counts = (int*)(ws + 0);                            // 64 B
  int*    sel01  = (int*)(ws + 1024);                         // 16384
  float2* w01    = (float2*)(ws + 20480);                     // 32768
  int*    tokidx = (int*)(ws + 53248);                        // 131072
  float*  rww    = (float*)(ws + 184320);                     // 131072
  unsigned short* xbf   = (unsigned short*)(ws + 315392);     // 8388608
  unsigned short* w1bf  = (unsigned short*)(ws + 8704000);    // 33554432
  unsigned short* w3bf  = (unsigned short*)(ws + 42258432);   // 33554432
  unsigned short* gated = (unsigned short*)(ws + 75812864);   // 37748736
  const size_t base_end = 113561600;
  bool big = ws_size >= base_end + 33554432;                  // +32MB for w2bf
  unsigned short* w2bf = big ? (unsigned short*)(ws + base_end) : w1bf;

  int nconvblk = (big ? 3 : 2) * NC32;
  front_kernel<<<TT + nconvblk, 256, 0, stream>>>(
      x, gw, w1, w3, w2, out_logits, final_out, xbf, w1bf, w3bf, w2bf,
      sel01, w01);
  build_kernel<<<EE, 256, 0, stream>>>(sel01, w01, counts, tokidx, rww);
  up_gate_kernel<<<dim3(FF / 64, TT / 128, EE), 256, 0, stream>>>(
      xbf, w1bf, w3bf, counts, tokidx, gated);
  if (!big) conv_kernel<<<NC32, 256, 0, stream>>>(w2, w1bf);
  down_kernel<<<dim3(HH / 128, TT / 128, EE), 256, 0, stream>>>(
      gated, w2bf, counts, tokidx, rww, final_out);
}

// Round 13
// 251.864 us; speedup vs baseline: 1.5380x; 1.0692x over previous
//
#include <hip/hip_runtime.h>
#include <hip/hip_bf16.h>

// MoE: B=2,S=2048 -> T=4096 tokens, H=1024, F=2048, E=8, TOPK=2
#define TT 4096
#define HH 1024
#define FF 2048
#define EE 8
#define NC32 2048   // EE*FF*HH / (256*32) conv chunks per weight tensor
#define LDSU 32768  // LDS slot stride (bytes)

typedef short short8_t __attribute__((ext_vector_type(8)));
typedef float f32x4 __attribute__((ext_vector_type(4)));

__device__ __forceinline__ unsigned short f2b(float f) {
  union { float f; unsigned u; } v; v.f = f;
  return (unsigned short)((v.u + 0x7fffu + ((v.u >> 16) & 1u)) >> 16);  // RNE
}

__device__ __forceinline__ void gload16(const unsigned short* g, void* l) {
  __builtin_amdgcn_global_load_lds(
      (const __attribute__((address_space(1))) void*)g,
      (__attribute__((address_space(3))) void*)l, 16, 0, 0);
}

#define FENCE asm volatile("" ::: "memory")

// Batched-ILP f32->bf16 conv: 8 independent float4 loads in flight per thread.
__device__ __forceinline__ void conv_ilp(const float* __restrict__ src,
                                         unsigned short* __restrict__ dst,
                                         int c, int tid) {
  size_t base = (size_t)c * 8192 + tid * 4;
  float4 v[8];
#pragma unroll
  for (int j = 0; j < 8; ++j)
    v[j] = *reinterpret_cast<const float4*>(src + base + j * 1024);
#pragma unroll
  for (int j = 0; j < 8; ++j) {
    ushort4 b4;
    b4.x = f2b(v[j].x); b4.y = f2b(v[j].y); b4.z = f2b(v[j].z); b4.w = f2b(v[j].w);
    *reinterpret_cast<ushort4*>(dst + base + j * 1024) = b4;
  }
}

// -------- Front: router (atomic-free) + batched-ILP w1/w3[/w2] convs ------------
__global__ __launch_bounds__(256) void front_kernel(
    const float* __restrict__ x, const float* __restrict__ gw,
    const float* __restrict__ w1, const float* __restrict__ w3,
    const float* __restrict__ w2,
    float* __restrict__ out_logits,
    unsigned short* __restrict__ xbf,
    unsigned short* __restrict__ w1bf, unsigned short* __restrict__ w3bf,
    unsigned short* __restrict__ w2bf,
    int* __restrict__ sel01, float2* __restrict__ w01)
{
  int tid = threadIdx.x;
  int b = blockIdx.x;
  if (b >= TT) {
    int cb = b - TT;
    if (cb < NC32)          conv_ilp(w1, w1bf, cb, tid);
    else if (cb < 2 * NC32) conv_ilp(w3, w3bf, cb - NC32, tid);
    else                    conv_ilp(w2, w2bf, cb - 2 * NC32, tid);
    return;
  }
  int t = b;

  __shared__ float xs[HH];
  __shared__ float lg[EE];

  float4 v = reinterpret_cast<const float4*>(x + (size_t)t * HH)[tid];
  xs[tid * 4 + 0] = v.x; xs[tid * 4 + 1] = v.y;
  xs[tid * 4 + 2] = v.z; xs[tid * 4 + 3] = v.w;
  ushort4 b4;
  b4.x = f2b(v.x); b4.y = f2b(v.y); b4.z = f2b(v.z); b4.w = f2b(v.w);
  reinterpret_cast<ushort4*>(xbf + (size_t)t * HH)[tid] = b4;
  __syncthreads();

  int lane = tid & 63, wv = tid >> 6;
  for (int e = wv; e < EE; e += 4) {
    float s = 0.f;
    const float* g = gw + (size_t)e * HH;
#pragma unroll
    for (int j = 0; j < HH / 64; ++j) s += xs[lane + j * 64] * g[lane + j * 64];
#pragma unroll
    for (int off = 32; off > 0; off >>= 1) s += __shfl_down(s, off);
    if (lane == 0) lg[e] = s;
  }
  __syncthreads();

  if (tid < 8) out_logits[(size_t)t * EE + tid] = lg[tid];
  if (tid == 0) {
    float l[EE];
#pragma unroll
    for (int e = 0; e < EE; ++e) l[e] = lg[e];
    int e0 = 0;
#pragma unroll
    for (int e = 1; e < EE; ++e) if (l[e] > l[e0]) e0 = e;
    int e1 = -1;
#pragma unroll
    for (int e = 0; e < EE; ++e) if (e != e0 && (e1 < 0 || l[e] > l[e1])) e1 = e;
    float p1 = expf(l[e1] - l[e0]);
    float w0 = 1.f / (1.f + p1);
    float w1v = p1 * w0;
    sel01[t] = e0 | (e1 << 8);
    w01[t] = make_float2(w0, w1v);
  }
}

// -------- Build: per-expert compacted token lists, atomic-free, deterministic ----
__global__ __launch_bounds__(256) void build_kernel(
    const int* __restrict__ sel01, const float2* __restrict__ w01,
    int* __restrict__ counts, int* __restrict__ tokidx, float* __restrict__ rww)
{
  int e = blockIdx.x;
  int tid = threadIdx.x, lane = tid & 63, wv = tid >> 6;
  __shared__ int wsum[4];
  int base = 0;
  for (int t0 = 0; t0 < TT; t0 += 256) {
    int t = t0 + tid;
    int s = sel01[t];
    int e0 = s & 255, e1 = (s >> 8) & 255;
    bool hit = (e0 == e) || (e1 == e);
    float w = 0.f;
    if (hit) { float2 ww = w01[t]; w = (e0 == e) ? ww.x : ww.y; }
    unsigned long long m = __ballot(hit);
    int wpre = __popcll(m & ((1ull << lane) - 1));
    if (lane == 63) wsum[wv] = wpre + (hit ? 1 : 0);
    __syncthreads();
    int wbase = base;
    for (int q = 0; q < wv; ++q) wbase += wsum[q];
    if (hit) {
      int pos = wbase + wpre;
      tokidx[e * TT + pos] = t;
      rww[e * TT + pos] = w;
    }
    base += wsum[0] + wsum[1] + wsum[2] + wsum[3];
    __syncthreads();
  }
  if (tid == 0) counts[e] = base;
}

// -------- Standalone conv for w2 (fallback when ws too small: after up_gate) ----
__global__ __launch_bounds__(256) void conv_kernel(
    const float* __restrict__ src, unsigned short* __restrict__ dst)
{
  conv_ilp(src, dst, blockIdx.x, threadIdx.x);
}

// -------- Combine: final = slot0 + slot1 (each token has exactly 2 experts) -----
__global__ __launch_bounds__(256) void combine_kernel(
    const float4* __restrict__ s0, const float4* __restrict__ s1,
    float4* __restrict__ out)
{
  size_t i = (size_t)blockIdx.x * 256 + threadIdx.x;
  float4 a = s0[i], b = s1[i];
  float4 r;
  r.x = a.x + b.x; r.y = a.y + b.y; r.z = a.z + b.z; r.w = a.w + b.w;
  out[i] = r;
}

// -------- Up-proj + gate: BK=64, 2-slot counted-vmcnt, 2 sub-phases + setprio ---
// Slot layout (bytes): A[0,16384) 128x64, B1[16384,24576) 64x64, B3[24576,32768).
// Swizzle: 16B-block index ^= (row & 7); pre-swizzled global SOURCE at stage time
// (LDS dest linear, per global_load_lds semantics) + swizzled ds_read address.
__global__ __launch_bounds__(256) void up_gate_kernel(
    const unsigned short* __restrict__ xbf,
    const unsigned short* __restrict__ w1bf, const unsigned short* __restrict__ w3bf,
    const int* __restrict__ counts, const int* __restrict__ tokidx,
    unsigned short* __restrict__ gated)
{
  int e = blockIdx.z;
  int n = counts[e];
  int row0 = blockIdx.y * 128;
  if (row0 >= n) return;
  int fbase = blockIdx.x * 64;

  int pe = 0;
  for (int q = 0; q < e; ++q) pe += (counts[q] + 127) & ~127;

  __shared__ __align__(16) char lds[2 * LDSU];   // 64 KB

  int tid = threadIdx.x;
  int lane = tid & 63, wv = tid >> 6;
  int sb = (tid & 7) ^ ((tid >> 3) & 7);   // swizzled source 16B-block

  const unsigned short* ga[4];
#pragma unroll
  for (int j = 0; j < 4; ++j) {
    int r = min(row0 + (tid >> 3) + 32 * j, n - 1);
    ga[j] = xbf + (size_t)tokidx[e * TT + r] * HH + sb * 8;
  }
  const unsigned short* gb1[2];
  const unsigned short* gb3[2];
#pragma unroll
  for (int j = 0; j < 2; ++j) {
    size_t rw_ = (size_t)e * FF + fbase + (tid >> 3) + 32 * j;
    gb1[j] = w1bf + rw_ * HH + sb * 8;
    gb3[j] = w3bf + rw_ * HH + sb * 8;
  }

  int wr = (wv >> 1) * 64, wc = (wv & 1) * 32;
  int fr = lane & 15, kq = lane >> 4, l7 = lane & 7;

  f32x4 acc1[4][2], acc3[4][2];
#pragma unroll
  for (int m = 0; m < 4; ++m)
#pragma unroll
    for (int nn = 0; nn < 2; ++nn) { acc1[m][nn] = (f32x4)0.f; acc3[m][nn] = (f32x4)0.f; }

#define UG_STAGE(T, SOFF) do {                                                     \
    _Pragma("unroll") for (int j = 0; j < 4; ++j)                                  \
      gload16(ga[j] + (T) * 64, lds + (SOFF) + j * 4096 + wv * 1024);              \
    _Pragma("unroll") for (int j = 0; j < 2; ++j) {                                \
      gload16(gb1[j] + (T) * 64, lds + (SOFF) + 16384 + j * 4096 + wv * 1024);     \
      gload16(gb3[j] + (T) * 64, lds + (SOFF) + 24576 + j * 4096 + wv * 1024);     \
    } } while (0)

#define UG_PHASE(SOFF, KS) do {                                                             \
    int bswz = (((KS) * 4 + kq) ^ l7) * 16;                                                 \
    short8_t a[4], b1f[2], b3f[2];                                                          \
    _Pragma("unroll") for (int m = 0; m < 4; ++m)                                           \
      a[m] = *(const short8_t*)(lds + (SOFF) + (wr + m * 16 + fr) * 128 + bswz);            \
    _Pragma("unroll") for (int nn = 0; nn < 2; ++nn) {                                      \
      b1f[nn] = *(const short8_t*)(lds + (SOFF) + 16384 + (wc + nn * 16 + fr) * 128 + bswz); \
      b3f[nn] = *(const short8_t*)(lds + (SOFF) + 24576 + (wc + nn * 16 + fr) * 128 + bswz); \
    }                                                                                       \
    __builtin_amdgcn_s_setprio(1);                                                          \
    _Pragma("unroll") for (int m = 0; m < 4; ++m)                                           \
      _Pragma("unroll") for (int nn = 0; nn < 2; ++nn) {                                    \
        acc1[m][nn] = __builtin_amdgcn_mfma_f32_16x16x32_bf16(a[m], b1f[nn], acc1[m][nn], 0, 0, 0); \
        acc3[m][nn] = __builtin_amdgcn_mfma_f32_16x16x32_bf16(a[m], b3f[nn], acc3[m][nn], 0, 0, 0); \
      }                                                                                     \
    __builtin_amdgcn_s_setprio(0);                                                          \
  } while (0)

#define UG_NT 16
#define UG_ITER(T, SOFF) do {                                          \
    if ((T) < UG_NT - 1) asm volatile("s_waitcnt vmcnt(8)" ::: "memory"); \
    else                 asm volatile("s_waitcnt vmcnt(0)" ::: "memory"); \
    __builtin_amdgcn_s_barrier(); FENCE;                               \
    UG_PHASE(SOFF, 0);                                                 \
    FENCE; __builtin_amdgcn_s_barrier(); FENCE;                        \
    UG_PHASE(SOFF, 1);                                                 \
    FENCE; __builtin_amdgcn_s_barrier(); FENCE;                        \
    if ((T) + 2 < UG_NT) UG_STAGE((T) + 2, SOFF);                      \
  } while (0)

  UG_STAGE(0, 0);
  UG_STAGE(1, LDSU);
  for (int t2 = 0; t2 < UG_NT; t2 += 2) { UG_ITER(t2, 0); UG_ITER(t2 + 1, LDSU); }
#undef UG_STAGE
#undef UG_PHASE
#undef UG_ITER

  // epilogue: gated = silu(h1)*h3 -> bf16
  size_t gbase = ((size_t)pe + row0) * FF + fbase;
#pragma unroll
  for (int m = 0; m < 4; ++m) {
#pragma unroll
    for (int nn = 0; nn < 2; ++nn) {
      f32x4 h1v = acc1[m][nn], h3v = acc3[m][nn];
#pragma unroll
      for (int j = 0; j < 4; ++j) {
        float z = h1v[j];
        float val = (z / (1.f + expf(-z))) * h3v[j];
        int r = wr + m * 16 + (lane >> 4) * 4 + j;
        int c = wc + nn * 16 + fr;
        gated[gbase + (size_t)r * FF + c] = f2b(val);
      }
    }
  }
}

// -------- Down-proj: BK=64, 2-slot counted-vmcnt, 2 sub-phases; slot stores -----
// Slot layout (bytes): A[0,16384) 128x64, B[16384,32768) 128x64.
// Epilogue: plain stores to slots[sl][t][h] (sl = which of token's 2 experts).
__global__ __launch_bounds__(256) void down_kernel(
    const unsigned short* __restrict__ gated,
    const unsigned short* __restrict__ w2bf,
    const int* __restrict__ counts, const int* __restrict__ tokidx,
    const float* __restrict__ rww, const int* __restrict__ sel01,
    float* __restrict__ slots)
{
  int e = blockIdx.z;
  int n = counts[e];
  int row0 = blockIdx.y * 128;
  if (row0 >= n) return;
  int hbase = blockIdx.x * 128;
  int valid = min(128, n - row0);

  int pe = 0;
  for (int q = 0; q < e; ++q) pe += (counts[q] + 127) & ~127;

  __shared__ __align__(16) char lds[2 * LDSU];   // 64 KB

  int tid = threadIdx.x;
  int lane = tid & 63, wv = tid >> 6;
  int sb = (tid & 7) ^ ((tid >> 3) & 7);

  const unsigned short* ga[4];
  const unsigned short* gb[4];
#pragma unroll
  for (int j = 0; j < 4; ++j) {
    ga[j] = gated + ((size_t)pe + row0 + (tid >> 3) + 32 * j) * FF + sb * 8;
    gb[j] = w2bf + ((size_t)e * HH + hbase + (tid >> 3) + 32 * j) * FF + sb * 8;
  }

  int wr = (wv >> 1) * 64, wc = (wv & 1) * 64;
  int fr = lane & 15, kq = lane >> 4, l7 = lane & 7;

  f32x4 acc[4][4];
#pragma unroll
  for (int m = 0; m < 4; ++m)
#pragma unroll
    for (int nn = 0; nn < 4; ++nn) acc[m][nn] = (f32x4)0.f;

#define DN_STAGE(T, SOFF) do {                                                   \
    _Pragma("unroll") for (int j = 0; j < 4; ++j) {                              \
      gload16(ga[j] + (T) * 64, lds + (SOFF) + j * 4096 + wv * 1024);            \
      gload16(gb[j] + (T) * 64, lds + (SOFF) + 16384 + j * 4096 + wv * 1024);    \
    } } while (0)

#define DN_PHASE(SOFF, KS) do {                                                            \
    int bswz = (((KS) * 4 + kq) ^ l7) * 16;                                                \
    short8_t a[4], bf[4];                                                                  \
    _Pragma("unroll") for (int m = 0; m < 4; ++m)                                          \
      a[m] = *(const short8_t*)(lds + (SOFF) + (wr + m * 16 + fr) * 128 + bswz);           \
    _Pragma("unroll") for (int nn = 0; nn < 4; ++nn)                                       \
      bf[nn] = *(const short8_t*)(lds + (SOFF) + 16384 + (wc + nn * 16 + fr) * 128 + bswz); \
    __builtin_amdgcn_s_setprio(1);                                                         \
    _Pragma("unroll") for (int m = 0; m < 4; ++m)                                          \
      _Pragma("unroll") for (int nn = 0; nn < 4; ++nn)                                     \
        acc[m][nn] = __builtin_amdgcn_mfma_f32_16x16x32_bf16(a[m], bf[nn], acc[m][nn], 0, 0, 0); \
    __builtin_amdgcn_s_setprio(0);                                                         \
  } while (0)

#define DN_NT 32
#define DN_ITER(T, SOFF) do {                                          \
    if ((T) < DN_NT - 1) asm volatile("s_waitcnt vmcnt(8)" ::: "memory"); \
    else                 asm volatile("s_waitcnt vmcnt(0)" ::: "memory"); \
    __builtin_amdgcn_s_barrier(); FENCE;                               \
    DN_PHASE(SOFF, 0);                                                 \
    FENCE; __builtin_amdgcn_s_barrier(); FENCE;                        \
    DN_PHASE(SOFF, 1);                                                 \
    FENCE; __builtin_amdgcn_s_barrier(); FENCE;                        \
    if ((T) + 2 < DN_NT) DN_STAGE((T) + 2, SOFF);                      \
  } while (0)

  DN_STAGE(0, 0);
  DN_STAGE(1, LDSU);
  for (int t2 = 0; t2 < DN_NT; t2 += 2) { DN_ITER(t2, 0); DN_ITER(t2 + 1, LDSU); }
#undef DN_STAGE
#undef DN_PHASE
#undef DN_ITER

  // epilogue: slots[sl][t][h] = rw * out  (plain stores, no atomics; each (t,sl)
  // written exactly once since each token appears once per expert list)
#pragma unroll
  for (int m = 0; m < 4; ++m) {
    int rbase = wr + m * 16 + (lane >> 4) * 4;
#pragma unroll
    for (int j = 0; j < 4; ++j) {
      int r = rbase + j;
      if (r < valid) {
        int t = tokidx[e * TT + row0 + r];
        float w = rww[e * TT + row0 + r];
        int sl = ((sel01[t] & 255) == e) ? 0 : 1;
        float* dst = slots + (size_t)sl * TT * HH + (size_t)t * HH;
#pragma unroll
        for (int nn = 0; nn < 4; ++nn) {
          int c = hbase + wc + nn * 16 + fr;
          dst[c] = w * acc[m][nn][j];
        }
      }
    }
  }
}

extern "C" void kernel_launch(void* const* d_in, const int* in_sizes, int n_in,
                              void* d_out, int out_size, void* d_ws, size_t ws_size,
                              hipStream_t stream) {
  const float* x  = (const float*)d_in[0];   // [T, H]
  const float* gw = (const float*)d_in[1];   // [E, H]
  const float* w1 = (const float*)d_in[2];   // [E, F, H]
  const float* w2 = (const float*)d_in[3];   // [E, H, F]
  const float* w3 = (const float*)d_in[4];   // [E, F, H]

  float* final_out  = (float*)d_out;                       // [T, H]
  float* out_logits = final_out + (size_t)TT * HH;         // [T, E]

  char* ws = (char*)d_ws;
  int*    counts = (int*)(ws + 0);                            // 64 B
  int*    sel01  = (int*)(ws + 1024);                         // 16384
  float2* w01    = (float2*)(ws + 20480);                     // 32768
  int*    tokidx = (int*)(ws + 53248);                        // 131072
  float*  rww    = (float*)(ws + 184320);                     // 131072
  unsigned short* xbf   = (unsigned short*)(ws + 315392);     // 8388608
  unsigned short* w1bf  = (unsigned short*)(ws + 8704000);    // 33554432
  unsigned short* w3bf  = (unsigned short*)(ws + 42258432);   // 33554432
  unsigned short* gated = (unsigned short*)(ws + 75812864);   // 37748736
  const size_t base_end = 113561600;
  bool big = ws_size >= base_end + 33554432;                  // +32MB for w2bf
  unsigned short* w2bf = big ? (unsigned short*)(ws + base_end) : w1bf;
  // down-proj output slots [2][T][H] f32 = 32MB, aliasing w3bf (dead after up_gate)
  float* slots = (float*)w3bf;

  int nconvblk = (big ? 3 : 2) * NC32;
  front_kernel<<<TT + nconvblk, 256, 0, stream>>>(
      x, gw, w1, w3, w2, out_logits, xbf, w1bf, w3bf, w2bf, sel01, w01);
  build_kernel<<<EE, 256, 0, stream>>>(sel01, w01, counts, tokidx, rww);
  up_gate_kernel<<<dim3(FF / 64, TT / 128, EE), 256, 0, stream>>>(
      xbf, w1bf, w3bf, counts, tokidx, gated);
  if (!big) conv_kernel<<<NC32, 256, 0, stream>>>(w2, w1bf);
  down_kernel<<<dim3(HH / 128, TT / 128, EE), 256, 0, stream>>>(
      gated, w2bf, counts, tokidx, rww, sel01, slots);
  combine_kernel<<<TT * HH / 1024, 256, 0, stream>>>(
      (const float4*)slots, (const float4*)(slots + (size_t)TT * HH),
      (float4*)final_out);
}